// Round 6
// baseline (430.172 us; speedup 1.0000x reference)
//
#include <hip/hip_runtime.h>
#include <hip/hip_bf16.h>
#include <stdint.h>

#define N 8192
#define D 128
#define ROWS   64                  // sim rows per block
#define JSTEP  64                  // sim cols per stage
#define NSTEPS 16                  // stages per block
#define JSEG   (JSTEP * NSTEPS)    // 1024 cols per block band
#define GRID_X (N / JSEG)          // 8
#define GRID_Y (N / ROWS)          // 128
#define NBLOCKS (GRID_X * GRID_Y)  // 1024 partials

typedef __bf16 bf16x8_t __attribute__((ext_vector_type(8)));
typedef __bf16 bf16x2_t __attribute__((ext_vector_type(2)));
typedef float  f32x4_t  __attribute__((ext_vector_type(4)));

// --- Kernel 1: row-normalize embeddings, cast to bf16 into workspace -------
__global__ __launch_bounds__(256) void normalize_k(const float* __restrict__ emb,
                                                   __bf16* __restrict__ xb) {
    const int row  = blockIdx.x * 4 + (threadIdx.x >> 6);
    const int lane = threadIdx.x & 63;
    const float2* src = reinterpret_cast<const float2*>(emb + (size_t)row * D);
    float2 v = src[lane];
    float ss = v.x * v.x + v.y * v.y;
#pragma unroll
    for (int off = 32; off; off >>= 1) ss += __shfl_xor(ss, off);
    const float inv = 1.0f / fmaxf(sqrtf(ss), 1e-8f);
    bf16x2_t o;
    o.x = (__bf16)(v.x * inv);
    o.y = (__bf16)(v.y * inv);
    *reinterpret_cast<bf16x2_t*>(xb + (size_t)row * D + lane * 2) = o;
}

// Async global->LDS 16B copy (no VGPR round-trip, no compiler wait-batching).
__device__ __forceinline__ void glds16(const float* g, float* l) {
    __builtin_amdgcn_global_load_lds(
        (const __attribute__((address_space(1))) void*)g,
        (__attribute__((address_space(3))) void*)l,
        16, 0, 0);
}

// --- Kernel 2: fused X*X^T + MSE, sim staged via global_load_lds -----------
// R5 post-mortem: register-carried prefetch is defeated by compiler waitcnt
// batching (~serial 900cy/load). m97-proven alternative: async stage sim
// tiles into LDS; the ONLY wait is the barrier, and stage t+1 is issued
// right AFTER barrier t so it flies during the whole compute phase of t.
// Block: 64 rows x 1024-col band, 16 steps of 64x64 fp32 sim (16KB),
// double-buffered (32KB LDS). Wave w owns rows [w*16,w*16+16).
__global__ __launch_bounds__(256, 4) void gemm_loss_k(const __bf16* __restrict__ xb,
                                                      const float* __restrict__ sim,
                                                      float* __restrict__ partials) {
    __shared__ float sbuf[2][ROWS * JSTEP];   // 2 x 16 KB
    __shared__ float wsum[4];

    const int lane = threadIdx.x & 63;
    const int wave = threadIdx.x >> 6;
    const int m = lane & 15;   // A row / B col; C col
    const int q = lane >> 4;   // k-quad; C row-quad
    const int i0 = blockIdx.y * ROWS;          // block's first sim row
    const int jb = blockIdx.x * JSEG;          // block's first sim col

    // a-frags fixed for whole kernel: rows i0 + wave*16 + m, 16 VGPRs.
    bf16x8_t a[4];
#pragma unroll
    for (int kk = 0; kk < 4; ++kk)
        a[kk] = *reinterpret_cast<const bf16x8_t*>(
            xb + (size_t)(i0 + wave * 16 + m) * D + kk * 32 + q * 8);

    // Stage issue: wave w, pass p copies rows {p*16+w*4 .. +4} x 64 cols.
    // LDS dest is wave-uniform base + lane*16 (hardware rule) == row-major.
    const int srow = (lane >> 4);          // 0..3 within pass
    const int scol = (lane & 15) * 4;      // 0,4,..,60
    // lambda-free helper via macro-ish inline loop below.

    // ---- prologue: issue stage 0 ----
    {
        const int jc = jb;
#pragma unroll
        for (int p = 0; p < 4; ++p) {
            const int rl = p * 16 + wave * 4;
            glds16(sim + (size_t)(i0 + rl + srow) * N + jc + scol,
                   &sbuf[0][rl * JSTEP]);
        }
    }

    float local = 0.0f;
    const f32x4_t zero = {0.0f, 0.0f, 0.0f, 0.0f};

#pragma unroll 2
    for (int t = 0; t < NSTEPS; ++t) {
        const int cur = t & 1;
        __syncthreads();   // drains this wave's glds(t); all readers of buf cur^1 done
        // ---- issue stage t+1 (flies during compute of t) ----
        if (t + 1 < NSTEPS) {
            const int jc = jb + (t + 1) * JSTEP;
#pragma unroll
            for (int p = 0; p < 4; ++p) {
                const int rl = p * 16 + wave * 4;
                glds16(sim + (size_t)(i0 + rl + srow) * N + jc + scol,
                       &sbuf[cur ^ 1][rl * JSTEP]);
            }
        }
        // ---- compute step t: 16 rows x 64 cols, K=128 ----
        const int jc = jb + t * JSTEP;
        f32x4_t acc[4];
#pragma unroll
        for (int s = 0; s < 4; ++s) acc[s] = zero;
#pragma unroll
        for (int kk = 0; kk < 4; ++kk) {
#pragma unroll
            for (int s = 0; s < 4; ++s) {
                bf16x8_t b = *reinterpret_cast<const bf16x8_t*>(
                    xb + (size_t)(jc + s * 16 + m) * D + kk * 32 + q * 8);
                acc[s] = __builtin_amdgcn_mfma_f32_16x16x32_bf16(a[kk], b, acc[s], 0, 0, 0);
            }
        }
        // ---- fused (pred - sim)^2 from LDS (C layout: row=w16+q*4+r, col=s*16+m)
#pragma unroll
        for (int s = 0; s < 4; ++s)
#pragma unroll
            for (int r = 0; r < 4; ++r) {
                const float sv = sbuf[cur][(wave * 16 + q * 4 + r) * JSTEP + s * 16 + m];
                const float d = acc[s][r] - sv;
                local = fmaf(d, d, local);
            }
    }

#pragma unroll
    for (int off = 32; off; off >>= 1) local += __shfl_xor(local, off);
    if (lane == 0) wsum[wave] = local;
    __syncthreads();
    if (threadIdx.x == 0) {
        const int bid = blockIdx.y * gridDim.x + blockIdx.x;
        partials[bid] = wsum[0] + wsum[1] + wsum[2] + wsum[3];
    }
}

// --- Kernel 3: reduce 1024 partials, finalize ------------------------------
__global__ __launch_bounds__(256) void finalize_k(const float* __restrict__ partials,
                                                  float* __restrict__ out) {
    float s = 0.0f;
#pragma unroll
    for (int i = 0; i < NBLOCKS / 256; ++i)
        s += partials[i * 256 + threadIdx.x];
#pragma unroll
    for (int off = 32; off; off >>= 1) s += __shfl_xor(s, off);
    __shared__ float wsum[4];
    if ((threadIdx.x & 63) == 0) wsum[threadIdx.x >> 6] = s;
    __syncthreads();
    if (threadIdx.x == 0)
        out[0] = (wsum[0] + wsum[1] + wsum[2] + wsum[3])
                 * (1.0f / ((float)N * (float)N));
}

extern "C" void kernel_launch(void* const* d_in, const int* in_sizes, int n_in,
                              void* d_out, int out_size, void* d_ws, size_t ws_size,
                              hipStream_t stream) {
    const float* emb = (const float*)d_in[0];
    const float* sim = (const float*)d_in[1];
    __bf16* xb = (__bf16*)d_ws;                                   // 2 MB bf16 x
    float* partials = (float*)((char*)d_ws + (size_t)N * D * sizeof(__bf16));

    normalize_k<<<N / 4, 256, 0, stream>>>(emb, xb);
    gemm_loss_k<<<dim3(GRID_X, GRID_Y), 256, 0, stream>>>(xb, sim, partials);
    finalize_k<<<1, 256, 0, stream>>>(partials, (float*)d_out);
}